// Round 3
// baseline (491.959 us; speedup 1.0000x reference)
//
#include <hip/hip_runtime.h>
#include <hip/hip_bf16.h>

// MoE top-2/8, T=4096, H=2048, FFN=1024.
// Fused-conversion pipeline (no bf16 weight copies in HBM):
//   router  (router logits + x fp32->bf16 -> Xb)
//   compact (1 block, ballot prefix)
//   upproj  (A=Xb bf16 via global_load_lds, XOR-swizzled source;
//            B=W1/W3 fp32 -> cvt_pk -> swizzled LDS;
//            single-barrier double-buffered K-loop, counted-drain style)
//   downproj(same structure, B=W2 fp32)
//   combine

#define T_TOK 4096
#define H_DIM 2048
#define FFN_D 1024
#define NE    8

typedef __attribute__((ext_vector_type(8))) short          bf16x8;
typedef __attribute__((ext_vector_type(4))) float          f32x4;
typedef __attribute__((ext_vector_type(4))) unsigned short us4;
typedef __attribute__((ext_vector_type(8))) unsigned short us8;

#define RB_ROUTER 1024u

__device__ __forceinline__ unsigned short f2bf(float f) {
  unsigned u = __builtin_bit_cast(unsigned, f);
  u += 0x7fffu + ((u >> 16) & 1u);
  return (unsigned short)(u >> 16);
}
__device__ __forceinline__ float bf2f(unsigned short u) {
  return __builtin_bit_cast(float, ((unsigned)u) << 16);
}
// 8x fp32 -> 8x bf16 via v_cvt_pk_bf16_f32 (RNE)
__device__ __forceinline__ us8 f8bf(float4 a, float4 b) {
  union { us8 o; unsigned u[4]; } r;
  asm("v_cvt_pk_bf16_f32 %0, %1, %2" : "=v"(r.u[0]) : "v"(a.x), "v"(a.y));
  asm("v_cvt_pk_bf16_f32 %0, %1, %2" : "=v"(r.u[1]) : "v"(a.z), "v"(a.w));
  asm("v_cvt_pk_bf16_f32 %0, %1, %2" : "=v"(r.u[2]) : "v"(b.x), "v"(b.y));
  asm("v_cvt_pk_bf16_f32 %0, %1, %2" : "=v"(r.u[3]) : "v"(b.z), "v"(b.w));
  return r.o;
}
__device__ __forceinline__ void async16(const void* g, void* l) {
  __builtin_amdgcn_global_load_lds((const __attribute__((address_space(1))) void*)g,
                                   (__attribute__((address_space(3))) void*)l, 16, 0, 0);
}

// ---------------- K1: router (one wave per token) + x convert -> Xb ----
__global__ void router_kernel(const float* __restrict__ x,
                              const float* __restrict__ Wg,
                              const float* __restrict__ bias,
                              unsigned* __restrict__ epair,
                              float* __restrict__ wpair,
                              unsigned short* __restrict__ Xb) {
  const int wv   = threadIdx.x >> 6;
  const int lane = threadIdx.x & 63;
  const int t    = blockIdx.x * 4 + wv;

  const float4* xr = (const float4*)(x + (size_t)t * H_DIM);
  us4*          xb = (us4*)(Xb + (size_t)t * H_DIM);

  float acc[NE];
#pragma unroll
  for (int e = 0; e < NE; e++) acc[e] = 0.f;

#pragma unroll
  for (int j = 0; j < 8; j++) {
    int i4 = j * 64 + lane;
    float4 v = xr[i4];
    us4 d; d.x = f2bf(v.x); d.y = f2bf(v.y); d.z = f2bf(v.z); d.w = f2bf(v.w);
    xb[i4] = d;
#pragma unroll
    for (int e = 0; e < NE; e++) {
      float4 w = ((const float4*)(Wg + e * H_DIM))[i4];
      acc[e] += v.x * w.x + v.y * w.y + v.z * w.z + v.w * w.w;
    }
  }
#pragma unroll
  for (int e = 0; e < NE; e++) {
#pragma unroll
    for (int m = 32; m >= 1; m >>= 1) acc[e] += __shfl_xor(acc[e], m, 64);
  }

  if (lane == 0) {
    float sig[NE], sc[NE];
#pragma unroll
    for (int e = 0; e < NE; e++) {
      sig[e] = 1.f / (1.f + expf(-acc[e]));
      sc[e]  = sig[e] + bias[e];
    }
    int i1 = 0; float v1 = sc[0];
#pragma unroll
    for (int e = 1; e < NE; e++) if (sc[e] > v1) { v1 = sc[e]; i1 = e; }
    int i2 = -1; float v2 = -1e30f;
#pragma unroll
    for (int e = 0; e < NE; e++) if (e != i1 && sc[e] > v2) { v2 = sc[e]; i2 = e; }
    float w1 = sig[i1], w2 = sig[i2];
    float s = w1 + w2;
    epair[t] = (unsigned)i1 | ((unsigned)i2 << 8);
    wpair[2 * t]     = w1 / s;
    wpair[2 * t + 1] = w2 / s;
  }
}

// ---------------- K2: compaction, ONE block, 8 waves ----
__global__ void compact_kernel(const unsigned* __restrict__ epair,
                               const float* __restrict__ wpair,
                               int* __restrict__ cnt,
                               int* __restrict__ base,
                               int* __restrict__ rows,
                               float* __restrict__ wts,
                               int* __restrict__ t2s) {
  const int e    = threadIdx.x >> 6;
  const int lane = threadIdx.x & 63;
  const unsigned long long ltmask = ((unsigned long long)1 << lane) - 1;
  __shared__ int cnts[NE];

  int count = 0;
  for (int c = 0; c < T_TOK; c += 64) {
    int t = c + lane;
    unsigned ep = epair[t];
    bool m1 = ((ep & 255u) == (unsigned)e);
    bool m2 = (((ep >> 8) & 255u) == (unsigned)e);
    unsigned long long b1 = __ballot(m1);
    if (m1) {
      int p = count + __popcll(b1 & ltmask);
      rows[e * T_TOK + p] = t;
      wts [e * T_TOK + p] = wpair[2 * t];
      t2s[2 * t] = (e << 12) | p;
    }
    count += __popcll(b1);
    unsigned long long b2 = __ballot(m2);
    if (m2) {
      int p = count + __popcll(b2 & ltmask);
      rows[e * T_TOK + p] = t;
      wts [e * T_TOK + p] = wpair[2 * t + 1];
      t2s[2 * t + 1] = (e << 12) | p;
    }
    count += __popcll(b2);
  }
  if (lane == 0) { cnts[e] = count; cnt[e] = count; }
  __syncthreads();
  if (threadIdx.x == 0) {
    int s = 0;
    for (int i = 0; i < NE; i++) { base[i] = s; s += cnts[i]; }
    base[NE] = s;
  }
}

// ---------------- K3: up-proj BM=128 x BN=64 (x2 mats), BK=32, dbuf 1-barrier ----
__launch_bounds__(256)
__global__ void upproj_fast(const unsigned short* __restrict__ Xb,
                            const float* __restrict__ W1,
                            const float* __restrict__ W3,
                            const int* __restrict__ cnt,
                            const int* __restrict__ base,
                            const int* __restrict__ rows,
                            const float* __restrict__ wts,
                            unsigned short* __restrict__ G) {
  const int e  = blockIdx.z;
  const int m0 = blockIdx.y * 128;
  const int n0 = blockIdx.x * 64;
  const int ce = cnt[e];
  if (m0 >= ce) return;

  __shared__ __align__(16) unsigned short As [2][128 * 32];
  __shared__ __align__(16) unsigned short B1s[2][64 * 32];
  __shared__ __align__(16) unsigned short B3s[2][64 * 32];
  __shared__ int   t_ids[128];
  __shared__ float w_lds[128];

  const int tid = threadIdx.x;
  if (tid < 128) {
    int i = m0 + tid;
    if (i < ce) { t_ids[tid] = rows[e * T_TOK + i]; w_lds[tid] = wts[e * T_TOK + i]; }
    else        { t_ids[tid] = 0;                   w_lds[tid] = 0.f; }
  }
  __syncthreads();

  const int lane = tid & 63;
  const int wv   = tid >> 6;

  // swizzle terms: LDS slot (row, c') holds global 16B-col (c' ^ ((row>>1)&3))
  const int sA   = (lane >> 3) & 3;                 // = ((staged row)>>1)&3 for this lane
  const int gcol = ((lane & 3) ^ sA) * 8;           // A: pre-swizzled GLOBAL source col
  const int rxor = ((lane & 15) >> 1) & 3;          // read-side row swizzle
  const int qx   = (((lane >> 4) ^ rxor)) * 8;      // swizzled 16B col for frag reads

  const unsigned short* gA[2];
#pragma unroll
  for (int c = 0; c < 2; c++) {
    int r = wv * 32 + c * 16 + (lane >> 2);
    gA[c] = Xb + (size_t)t_ids[r] * H_DIM + gcol;
  }

  // B: fp32 source linear col; ds_write at swizzled col
  const int brow = n0 + wv * 16 + (lane >> 2);
  const float* gB1 = W1 + (size_t)e * FFN_D * H_DIM + (size_t)brow * H_DIM + (lane & 3) * 8;
  const float* gB3 = W3 + (size_t)e * FFN_D * H_DIM + (size_t)brow * H_DIM + (lane & 3) * 8;
  const int bidx = (wv * 16 + (lane >> 2)) * 32 + (((lane & 3) ^ sA)) * 8;

  const int wm = (wv & 1) * 64;
  const int wn = (wv >> 1) * 32;
  const int lr = lane & 15;

  f32x4 acc1[4][2], acc3[4][2];
#pragma unroll
  for (int mi = 0; mi < 4; mi++)
#pragma unroll
    for (int ni = 0; ni < 2; ni++) { acc1[mi][ni] = (f32x4)0.f; acc3[mi][ni] = (f32x4)0.f; }

  // ---- prologue: stage tile 0 into buf 0 ----
  async16(gA[0], &As[0][(wv * 32 + 0)  * 32 ]);
  async16(gA[1], &As[0][(wv * 32 + 16) * 32 ]);
  float4 p0 = *(const float4*)(gB1 + 0);
  float4 p1 = *(const float4*)(gB1 + 4);
  float4 p2 = *(const float4*)(gB3 + 0);
  float4 p3 = *(const float4*)(gB3 + 4);
  asm volatile("s_waitcnt vmcnt(0)" ::: "memory");
  *(us8*)&B1s[0][bidx] = f8bf(p0, p1);
  *(us8*)&B3s[0][bidx] = f8bf(p2, p3);
  __syncthreads();

  int cur = 0;
  for (int kt = 0; kt < H_DIM; kt += 32) {
    const int notlast = (kt + 32 < H_DIM);
    // issue next tile's loads first (covered by this tile's ds_read+MFMA)
    if (notlast) {
      async16(gA[0] + kt + 32, &As[cur ^ 1][(wv * 32 + 0)  * 32 ]);
      async16(gA[1] + kt + 32, &As[cur ^ 1][(wv * 32 + 16) * 32 ]);
      p0 = *(const float4*)(gB1 + kt + 32);
      p1 = *(const float4*)(gB1 + kt + 36);
      p2 = *(const float4*)(gB3 + kt + 32);
      p3 = *(const float4*)(gB3 + kt + 36);
    }
    __builtin_amdgcn_sched_barrier(0);

    bf16x8 a[4], b1[2], b3[2];
#pragma unroll
    for (int mi = 0; mi < 4; mi++)
      a[mi] = *(const bf16x8*)&As[cur][(wm + mi * 16 + lr) * 32 + qx];
#pragma unroll
    for (int ni = 0; ni < 2; ni++) {
      b1[ni] = *(const bf16x8*)&B1s[cur][(wn + ni * 16 + lr) * 32 + qx];
      b3[ni] = *(const bf16x8*)&B3s[cur][(wn + ni * 16 + lr) * 32 + qx];
    }
#pragma unroll
    for (int mi = 0; mi < 4; mi++)
#pragma unroll
      for (int ni = 0; ni < 2; ni++) {
        acc1[mi][ni] = __builtin_amdgcn_mfma_f32_16x16x32_bf16(a[mi], b1[ni], acc1[mi][ni], 0, 0, 0);
        acc3[mi][ni] = __builtin_amdgcn_mfma_f32_16x16x32_bf16(a[mi], b3[ni], acc3[mi][ni], 0, 0, 0);
      }

    if (notlast) {
      asm volatile("s_waitcnt vmcnt(0)" ::: "memory");   // next A in LDS, next B in regs
      *(us8*)&B1s[cur ^ 1][bidx] = f8bf(p0, p1);
      *(us8*)&B3s[cur ^ 1][bidx] = f8bf(p2, p3);
      asm volatile("s_waitcnt lgkmcnt(0)" ::: "memory"); // ds_writes visible
      __builtin_amdgcn_sched_barrier(0);
      __builtin_amdgcn_s_barrier();                      // raw: no vmcnt drain of in-flight
      __builtin_amdgcn_sched_barrier(0);
    }
    cur ^= 1;
  }

  const int be = base[e];
#pragma unroll
  for (int mi = 0; mi < 4; mi++)
#pragma unroll
    for (int ni = 0; ni < 2; ni++)
#pragma unroll
      for (int r = 0; r < 4; r++) {
        int row = wm + mi * 16 + (lane >> 4) * 4 + r;
        int col = wn + ni * 16 + lr;
        int i = m0 + row;
        if (i < ce) {
          float h1 = acc1[mi][ni][r];
          float h3 = acc3[mi][ni][r];
          float g  = h1 / (1.f + expf(-h1)) * h3 * w_lds[row];
          G[(size_t)(be + i) * FFN_D + n0 + col] = f2bf(g);
        }
      }
}

// ---------------- K4: down-proj BM=128 x BN=128, BK=32, dbuf 1-barrier ----
__launch_bounds__(256)
__global__ void downproj_fast(const unsigned short* __restrict__ G,
                              const float* __restrict__ W2,
                              const int* __restrict__ cnt,
                              const int* __restrict__ base,
                              unsigned short* __restrict__ Gd) {
  const int e  = blockIdx.z;
  const int m0 = blockIdx.y * 128;
  const int n0 = blockIdx.x * 128;
  const int ce = cnt[e];
  if (m0 >= ce) return;
  const int be = base[e];

  __shared__ __align__(16) unsigned short As[2][128 * 32];
  __shared__ __align__(16) unsigned short Bs[2][128 * 32];

  const int tid  = threadIdx.x;
  const int lane = tid & 63;
  const int wv   = tid >> 6;

  const int sA   = (lane >> 3) & 3;
  const int gcol = ((lane & 3) ^ sA) * 8;
  const int rxor = ((lane & 15) >> 1) & 3;
  const int qx   = (((lane >> 4) ^ rxor)) * 8;

  const unsigned short* gA[2];
#pragma unroll
  for (int c = 0; c < 2; c++) {
    int r = m0 + wv * 32 + c * 16 + (lane >> 2);
    if (r >= ce) r = ce - 1;
    gA[c] = G + (size_t)(be + r) * FFN_D + gcol;
  }

  const int rb0 = wv * 32 + (lane >> 2);
  const int rb1 = rb0 + 16;
  const float* gB0 = W2 + (size_t)e * H_DIM * FFN_D + (size_t)(n0 + rb0) * FFN_D + (lane & 3) * 8;
  const float* gB1 = W2 + (size_t)e * H_DIM * FFN_D + (size_t)(n0 + rb1) * FFN_D + (lane & 3) * 8;
  const int bw  = ((lane & 3) ^ sA) * 8;
  const int bi0 = rb0 * 32 + bw;
  const int bi1 = rb1 * 32 + bw;

  const int wm = (wv & 1) * 64;
  const int wn = (wv >> 1) * 64;
  const int lr = lane & 15;

  f32x4 acc[4][4];
#pragma unroll
  for (int mi = 0; mi < 4; mi++)
#pragma unroll
    for (int ni = 0; ni < 4; ni++) acc[mi][ni] = (f32x4)0.f;

  // ---- prologue: stage tile 0 into buf 0 ----
  async16(gA[0], &As[0][(wv * 32 + 0)  * 32 ]);
  async16(gA[1], &As[0][(wv * 32 + 16) * 32 ]);
  float4 p0 = *(const float4*)(gB0 + 0);
  float4 p1 = *(const float4*)(gB0 + 4);
  float4 p2 = *(const float4*)(gB1 + 0);
  float4 p3 = *(const float4*)(gB1 + 4);
  asm volatile("s_waitcnt vmcnt(0)" ::: "memory");
  *(us8*)&Bs[0][bi0] = f8bf(p0, p1);
  *(us8*)&Bs[0][bi1] = f8bf(p2, p3);
  __syncthreads();

  int cur = 0;
  for (int kt = 0; kt < FFN_D; kt += 32) {
    const int notlast = (kt + 32 < FFN_D);
    if (notlast) {
      async16(gA[0] + kt + 32, &As[cur ^ 1][(wv * 32 + 0)  * 32 ]);
      async16(gA[1] + kt + 32, &As[cur ^ 1][(wv * 32 + 16) * 32 ]);
      p0 = *(const float4*)(gB0 + kt + 32);
      p1 = *(const float4*)(gB0 + kt + 36);
      p2 = *(const float4*)(gB1 + kt + 32);
      p3 = *(const float4*)(gB1 + kt + 36);
    }
    __builtin_amdgcn_sched_barrier(0);

    bf16x8 a[4], b[4];
#pragma unroll
    for (int mi = 0; mi < 4; mi++)
      a[mi] = *(const bf16x8*)&As[cur][(wm + mi * 16 + lr) * 32 + qx];
#pragma unroll
    for (int ni = 0; ni < 4; ni++)
      b[ni] = *(const bf16x8*)&Bs[cur][(wn + ni * 16 + lr) * 32 + qx];
#pragma unroll
    for (int mi = 0; mi < 4; mi++)
#pragma unroll
      for (int ni = 0; ni < 4; ni++)
        acc[mi][ni] = __builtin_amdgcn_mfma_f32_16x16x32_bf16(a[mi], b[ni], acc[mi][ni], 0, 0, 0);

    if (notlast) {
      asm volatile("s_waitcnt vmcnt(0)" ::: "memory");
      *(us8*)&Bs[cur ^ 1][bi0] = f8bf(p0, p1);
      *(us8*)&Bs[cur ^ 1][bi1] = f8bf(p2, p3);
      asm volatile("s_waitcnt lgkmcnt(0)" ::: "memory");
      __builtin_amdgcn_sched_barrier(0);
      __builtin_amdgcn_s_barrier();
      __builtin_amdgcn_sched_barrier(0);
    }
    cur ^= 1;
  }

#pragma unroll
  for (int mi = 0; mi < 4; mi++)
#pragma unroll
    for (int ni = 0; ni < 4; ni++)
#pragma unroll
      for (int r = 0; r < 4; r++) {
        int row = wm + mi * 16 + (lane >> 4) * 4 + r;
        int col = wn + ni * 16 + lr;
        int i = m0 + row;
        if (i < ce)
          Gd[(size_t)(be + i) * H_DIM + n0 + col] = f2bf(acc[mi][ni][r]);
      }
}

// ---------------- K5: combine out[t] = Gd[slot1] + Gd[slot2] ----
__global__ void combine_kernel(const unsigned short* __restrict__ Gd,
                               const int* __restrict__ base,
                               const int* __restrict__ tok2slot,
                               float* __restrict__ out) {
  const int t = blockIdx.x;
  const int v1 = tok2slot[2 * t], v2 = tok2slot[2 * t + 1];
  const int s1 = base[v1 >> 12] + (v1 & 4095);
  const int s2 = base[v2 >> 12] + (v2 & 4095);
  const us4* r1 = (const us4*)(Gd + (size_t)s1 * H_DIM);
  const us4* r2 = (const us4*)(Gd + (size_t)s2 * H_DIM);
  float4* o = (float4*)(out + (size_t)t * H_DIM);
#pragma unroll
  for (int j = 0; j < 2; j++) {
    int i = j * 256 + threadIdx.x;
    us4 a = r1[i], b = r2[i];
    float4 r;
    r.x = bf2f(a.x) + bf2f(b.x);
    r.y = bf2f(a.y) + bf2f(b.y);
    r.z = bf2f(a.z) + bf2f(b.z);
    r.w = bf2f(a.w) + bf2f(b.w);
    o[i] = r;
  }
}

// ---------------- Launch ----------------
extern "C" void kernel_launch(void* const* d_in, const int* in_sizes, int n_in,
                              void* d_out, int out_size, void* d_ws, size_t ws_size,
                              hipStream_t stream) {
  (void)in_sizes; (void)n_in; (void)out_size; (void)ws_size;
  const float* x    = (const float*)d_in[0];
  const float* Wg   = (const float*)d_in[1];
  const float* W1   = (const float*)d_in[2];
  const float* W2   = (const float*)d_in[3];
  const float* W3   = (const float*)d_in[4];
  const float* bias = (const float*)d_in[5];
  float* out = (float*)d_out;

  char* ws = (char*)d_ws;
  const size_t OFF_CNT   = 0;
  const size_t OFF_BASE  = 64;
  const size_t OFF_T2S   = 1024;                       // 32 KB
  const size_t OFF_ROWS  = 65536;                      // 128 KB
  const size_t OFF_WTS   = OFF_ROWS + 131072;          // 128 KB
  const size_t OFF_EPAIR = OFF_WTS + 131072;           // 16 KB
  const size_t OFF_WPAIR = OFF_EPAIR + 16384;          // 32 KB
  const size_t OFF_XB    = 1048576;                    // 16 MB
  const size_t OFF_G     = OFF_XB + 16777216;          // 16 MB
  const size_t OFF_GD    = OFF_G + 16777216;           // 32 MB
  // total ~65 MB

  int*   cnt   = (int*)(ws + OFF_CNT);
  int*   base  = (int*)(ws + OFF_BASE);
  int*   t2s   = (int*)(ws + OFF_T2S);
  int*   rows  = (int*)(ws + OFF_ROWS);
  float* wts   = (float*)(ws + OFF_WTS);
  unsigned* epair = (unsigned*)(ws + OFF_EPAIR);
  float* wpair = (float*)(ws + OFF_WPAIR);
  unsigned short* Xb  = (unsigned short*)(ws + OFF_XB);
  unsigned short* G   = (unsigned short*)(ws + OFF_G);
  unsigned short* Gd  = (unsigned short*)(ws + OFF_GD);

  router_kernel<<<RB_ROUTER, 256, 0, stream>>>(x, Wg, bias, epair, wpair, Xb);

  compact_kernel<<<1, 512, 0, stream>>>(epair, wpair, cnt, base, rows, wts, t2s);

  dim3 g2(FFN_D / 64, T_TOK / 128, NE);
  upproj_fast<<<g2, 256, 0, stream>>>(Xb, W1, W3, cnt, base, rows, wts, G);

  dim3 g3(H_DIM / 128, T_TOK / 128, NE);
  downproj_fast<<<g3, 256, 0, stream>>>(G, W2, cnt, base, Gd);

  combine_kernel<<<T_TOK, 256, 0, stream>>>(Gd, base, t2s, out);
}

// Round 4
// 453.309 us; speedup vs baseline: 1.0853x; 1.0853x over previous
//
#include <hip/hip_runtime.h>
#include <hip/hip_bf16.h>

// MoE top-2/8, T=4096, H=2048, FFN=1024.
// R0 structure (bf16 weight copies + all-async16 GEMM staging) with a
// depth-2 / 3-buffer / counted-vmcnt pipeline in both GEMMs:
//   router_conv (router + W1/W3 fp32->bf16 convert, one grid)
//   compact     (1 block, ballot prefix)
//   upproj      (BK=32, 3-buf depth-2 global_load_lds pipeline, XOR swizzle;
//                z==NE slice converts W2 concurrently)
//   downproj    (same pipeline) -> combine.

#define T_TOK 4096
#define H_DIM 2048
#define FFN_D 1024
#define NE    8

typedef __attribute__((ext_vector_type(8))) short          bf16x8;
typedef __attribute__((ext_vector_type(4))) float          f32x4;
typedef __attribute__((ext_vector_type(4))) unsigned short us4;

#define N4_PER_W ((size_t)NE * FFN_D * H_DIM / 4)   // 4,194,304 float4 per weight tensor
#define RB_ROUTER 1024u                             // router blocks (4 tokens each)
#define CB_CONV   8192u                             // convert blocks for W1+W3

__device__ __forceinline__ unsigned short f2bf(float f) {
  unsigned u = __builtin_bit_cast(unsigned, f);
  u += 0x7fffu + ((u >> 16) & 1u);
  return (unsigned short)(u >> 16);
}
__device__ __forceinline__ float bf2f(unsigned short u) {
  return __builtin_bit_cast(float, ((unsigned)u) << 16);
}
// 4x fp32 -> 4x bf16 via v_cvt_pk_bf16_f32 (RNE, same rounding as f2bf)
__device__ __forceinline__ us4 f4bf(float4 v) {
  union { us4 o; unsigned u[2]; } r;
  asm("v_cvt_pk_bf16_f32 %0, %1, %2" : "=v"(r.u[0]) : "v"(v.x), "v"(v.y));
  asm("v_cvt_pk_bf16_f32 %0, %1, %2" : "=v"(r.u[1]) : "v"(v.z), "v"(v.w));
  return r.o;
}
__device__ __forceinline__ void async16(const void* g, void* l) {
  __builtin_amdgcn_global_load_lds((const __attribute__((address_space(1))) void*)g,
                                   (__attribute__((address_space(3))) void*)l, 16, 0, 0);
}

// ---------------- K1: router (blocks 0..1023) + W1/W3 convert (blocks 1024..9215) ----
__global__ void router_conv_kernel(const float* __restrict__ x,
                                   const float* __restrict__ Wg,
                                   const float* __restrict__ bias,
                                   unsigned* __restrict__ epair,
                                   float* __restrict__ wpair,
                                   unsigned short* __restrict__ Xb,
                                   const float* __restrict__ W1, unsigned short* __restrict__ W1b,
                                   const float* __restrict__ W3, unsigned short* __restrict__ W3b) {
  if (blockIdx.x >= RB_ROUTER) {
    size_t b0 = (size_t)(blockIdx.x - RB_ROUTER) * 1024;
#pragma unroll
    for (int k = 0; k < 4; k++) {
      size_t i = b0 + k * 256 + threadIdx.x;
      const float* s; unsigned short* d;
      if (i < N4_PER_W) { s = W1; d = W1b; } else { s = W3; d = W3b; i -= N4_PER_W; }
      float4 v = ((const float4*)s)[i];
      ((us4*)d)[i] = f4bf(v);
    }
    return;
  }
  const int wv   = threadIdx.x >> 6;
  const int lane = threadIdx.x & 63;
  const int t    = blockIdx.x * 4 + wv;

  const float4* xr = (const float4*)(x + (size_t)t * H_DIM);
  us4*          xb = (us4*)(Xb + (size_t)t * H_DIM);

  float acc[NE];
#pragma unroll
  for (int e = 0; e < NE; e++) acc[e] = 0.f;

#pragma unroll
  for (int j = 0; j < 8; j++) {
    int i4 = j * 64 + lane;
    float4 v = xr[i4];
    xb[i4] = f4bf(v);
#pragma unroll
    for (int e = 0; e < NE; e++) {
      float4 w = ((const float4*)(Wg + e * H_DIM))[i4];
      acc[e] += v.x * w.x + v.y * w.y + v.z * w.z + v.w * w.w;
    }
  }
#pragma unroll
  for (int e = 0; e < NE; e++) {
#pragma unroll
    for (int m = 32; m >= 1; m >>= 1) acc[e] += __shfl_xor(acc[e], m, 64);
  }

  if (lane == 0) {
    float sig[NE], sc[NE];
#pragma unroll
    for (int e = 0; e < NE; e++) {
      sig[e] = 1.f / (1.f + expf(-acc[e]));
      sc[e]  = sig[e] + bias[e];
    }
    int i1 = 0; float v1 = sc[0];
#pragma unroll
    for (int e = 1; e < NE; e++) if (sc[e] > v1) { v1 = sc[e]; i1 = e; }
    int i2 = -1; float v2 = -1e30f;
#pragma unroll
    for (int e = 0; e < NE; e++) if (e != i1 && sc[e] > v2) { v2 = sc[e]; i2 = e; }
    float w1 = sig[i1], w2 = sig[i2];
    float s = w1 + w2;
    epair[t] = (unsigned)i1 | ((unsigned)i2 << 8);
    wpair[2 * t]     = w1 / s;
    wpair[2 * t + 1] = w2 / s;
  }
}

// ---------------- K2: compaction, ONE block, 8 waves ----
__global__ void compact_kernel(const unsigned* __restrict__ epair,
                               const float* __restrict__ wpair,
                               int* __restrict__ cnt,
                               int* __restrict__ base,
                               int* __restrict__ rows,
                               float* __restrict__ wts,
                               int* __restrict__ t2s) {
  const int e    = threadIdx.x >> 6;
  const int lane = threadIdx.x & 63;
  const unsigned long long ltmask = ((unsigned long long)1 << lane) - 1;
  __shared__ int cnts[NE];

  int count = 0;
  for (int c = 0; c < T_TOK; c += 64) {
    int t = c + lane;
    unsigned ep = epair[t];
    bool m1 = ((ep & 255u) == (unsigned)e);
    bool m2 = (((ep >> 8) & 255u) == (unsigned)e);
    unsigned long long b1 = __ballot(m1);
    if (m1) {
      int p = count + __popcll(b1 & ltmask);
      rows[e * T_TOK + p] = t;
      wts [e * T_TOK + p] = wpair[2 * t];
      t2s[2 * t] = (e << 12) | p;
    }
    count += __popcll(b1);
    unsigned long long b2 = __ballot(m2);
    if (m2) {
      int p = count + __popcll(b2 & ltmask);
      rows[e * T_TOK + p] = t;
      wts [e * T_TOK + p] = wpair[2 * t + 1];
      t2s[2 * t + 1] = (e << 12) | p;
    }
    count += __popcll(b2);
  }
  if (lane == 0) { cnts[e] = count; cnt[e] = count; }
  __syncthreads();
  if (threadIdx.x == 0) {
    int s = 0;
    for (int i = 0; i < NE; i++) { base[i] = s; s += cnts[i]; }
    base[NE] = s;
  }
}

// ---------------- K3: up-proj BM=128 x BN=64 (x2 mats), BK=32.
// 3-buffer depth-2 async16 pipeline, counted vmcnt, raw barrier.
// blockIdx.z == NE: W2 fp32->bf16 convert slice. ----
__launch_bounds__(256)
__global__ void upproj_fast(const unsigned short* __restrict__ Xb,
                            const unsigned short* __restrict__ W1b,
                            const unsigned short* __restrict__ W3b,
                            const int* __restrict__ cnt,
                            const int* __restrict__ base,
                            const int* __restrict__ rows,
                            const float* __restrict__ wts,
                            unsigned short* __restrict__ G,
                            const float* __restrict__ W2, unsigned short* __restrict__ W2b) {
  if (blockIdx.z == NE) {
    size_t flat = (size_t)blockIdx.y * 16 + blockIdx.x;   // 0..511
    size_t b0 = flat * 8192;
#pragma unroll
    for (int k = 0; k < 32; k++) {
      size_t i = b0 + (size_t)k * 256 + threadIdx.x;
      float4 v = ((const float4*)W2)[i];
      ((us4*)W2b)[i] = f4bf(v);
    }
    return;
  }
  const int e  = blockIdx.z;
  const int m0 = blockIdx.y * 128;
  const int n0 = blockIdx.x * 64;
  const int ce = cnt[e];
  if (m0 >= ce) return;

  __shared__ __align__(16) unsigned short As [3][128 * 32];
  __shared__ __align__(16) unsigned short B1s[3][64 * 32];
  __shared__ __align__(16) unsigned short B3s[3][64 * 32];
  __shared__ int   t_ids[128];
  __shared__ float w_lds[128];

  const int tid = threadIdx.x;
  if (tid < 128) {
    int i = m0 + tid;
    if (i < ce) { t_ids[tid] = rows[e * T_TOK + i]; w_lds[tid] = wts[e * T_TOK + i]; }
    else        { t_ids[tid] = 0;                   w_lds[tid] = 0.f; }
  }
  __syncthreads();   // full drain: vmcnt==0 entering the pipeline

  const int lane = tid & 63;
  const int wv   = tid >> 6;

  // XOR swizzle (proven R3): LDS 16B-slot (row, c') holds global col (c' ^ ((row>>1)&3))
  const int sA   = (lane >> 3) & 3;
  const int gcol = ((lane & 3) ^ sA) * 8;        // pre-swizzled GLOBAL source col
  const int rxor = ((lane & 15) >> 1) & 3;
  const int qx   = ((lane >> 4) ^ rxor) * 8;     // swizzled col for fragment reads

  const unsigned short* gA[2];
#pragma unroll
  for (int c = 0; c < 2; c++) {
    int r = wv * 32 + c * 16 + (lane >> 2);
    gA[c] = Xb + (size_t)t_ids[r] * H_DIM + gcol;
  }
  const size_t wrow = (size_t)(n0 + wv * 16 + (lane >> 2));
  const unsigned short* gB1 = W1b + (size_t)e * FFN_D * H_DIM + wrow * H_DIM + gcol;
  const unsigned short* gB3 = W3b + (size_t)e * FFN_D * H_DIM + wrow * H_DIM + gcol;
  const int dA0 = (wv * 32 + 0)  * 32;
  const int dA1 = (wv * 32 + 16) * 32;
  const int dB  = (wv * 16) * 32;

  const int wm = (wv & 1) * 64;
  const int wn = (wv >> 1) * 32;
  const int lr = lane & 15;

  f32x4 acc1[4][2], acc3[4][2];
#pragma unroll
  for (int mi = 0; mi < 4; mi++)
#pragma unroll
    for (int ni = 0; ni < 2; ni++) { acc1[mi][ni] = (f32x4)0.f; acc3[mi][ni] = (f32x4)0.f; }

#define STAGE_UP(KT, BUF)                          \
  do {                                             \
    async16(gA[0] + (KT), &As [BUF][dA0]);         \
    async16(gA[1] + (KT), &As [BUF][dA1]);         \
    async16(gB1  + (KT), &B1s[BUF][dB]);           \
    async16(gB3  + (KT), &B3s[BUF][dB]);           \
  } while (0)

  // prologue: batches 0 and 1 in flight; wait for batch 0 only
  STAGE_UP(0, 0);
  STAGE_UP(32, 1);
  asm volatile("s_waitcnt vmcnt(4)" ::: "memory");
  __builtin_amdgcn_s_barrier();

  for (int k = 0; k < H_DIM / 32; ++k) {
    const int kt2 = (k + 2) * 32;
    const int cb  = k % 3;
    if (kt2 < H_DIM) STAGE_UP(kt2, (k + 2) % 3);
    __builtin_amdgcn_sched_barrier(0);

    bf16x8 a[4], b1[2], b3[2];
#pragma unroll
    for (int mi = 0; mi < 4; mi++)
      a[mi] = *(const bf16x8*)&As[cb][(wm + mi * 16 + lr) * 32 + qx];
#pragma unroll
    for (int ni = 0; ni < 2; ni++) {
      b1[ni] = *(const bf16x8*)&B1s[cb][(wn + ni * 16 + lr) * 32 + qx];
      b3[ni] = *(const bf16x8*)&B3s[cb][(wn + ni * 16 + lr) * 32 + qx];
    }
#pragma unroll
    for (int mi = 0; mi < 4; mi++)
#pragma unroll
      for (int ni = 0; ni < 2; ni++) {
        acc1[mi][ni] = __builtin_amdgcn_mfma_f32_16x16x32_bf16(a[mi], b1[ni], acc1[mi][ni], 0, 0, 0);
        acc3[mi][ni] = __builtin_amdgcn_mfma_f32_16x16x32_bf16(a[mi], b3[ni], acc3[mi][ni], 0, 0, 0);
      }

    // batch k+1 must have landed; batch k+2 (4 ops) may stay in flight
    if (kt2 < H_DIM) asm volatile("s_waitcnt vmcnt(4)" ::: "memory");
    else             asm volatile("s_waitcnt vmcnt(0)" ::: "memory");
    __builtin_amdgcn_sched_barrier(0);
    __builtin_amdgcn_s_barrier();
    __builtin_amdgcn_sched_barrier(0);
  }
#undef STAGE_UP

  const int be = base[e];
#pragma unroll
  for (int mi = 0; mi < 4; mi++)
#pragma unroll
    for (int ni = 0; ni < 2; ni++)
#pragma unroll
      for (int r = 0; r < 4; r++) {
        int row = wm + mi * 16 + (lane >> 4) * 4 + r;
        int col = wn + ni * 16 + lr;
        int i = m0 + row;
        if (i < ce) {
          float h1 = acc1[mi][ni][r];
          float h3 = acc3[mi][ni][r];
          float g  = h1 / (1.f + expf(-h1)) * h3 * w_lds[row];
          G[(size_t)(be + i) * FFN_D + n0 + col] = f2bf(g);
        }
      }
}

// ---------------- K4: down-proj BM=128 x BN=128, BK=32 -> bf16 Gd ----
__launch_bounds__(256)
__global__ void downproj_fast(const unsigned short* __restrict__ G,
                              const unsigned short* __restrict__ W2b,
                              const int* __restrict__ cnt,
                              const int* __restrict__ base,
                              unsigned short* __restrict__ Gd) {
  const int e  = blockIdx.z;
  const int m0 = blockIdx.y * 128;
  const int n0 = blockIdx.x * 128;
  const int ce = cnt[e];
  if (m0 >= ce) return;
  const int be = base[e];

  __shared__ __align__(16) unsigned short As[3][128 * 32];
  __shared__ __align__(16) unsigned short Bs[3][128 * 32];

  const int tid  = threadIdx.x;
  const int lane = tid & 63;
  const int wv   = tid >> 6;

  const int sA   = (lane >> 3) & 3;
  const int gcol = ((lane & 3) ^ sA) * 8;
  const int rxor = ((lane & 15) >> 1) & 3;
  const int qx   = ((lane >> 4) ^ rxor) * 8;

  const unsigned short* gA[2];
  const unsigned short* gB[2];
#pragma unroll
  for (int c = 0; c < 2; c++) {
    int r = m0 + wv * 32 + c * 16 + (lane >> 2);
    if (r >= ce) r = ce - 1;
    gA[c] = G + (size_t)(be + r) * FFN_D + gcol;
    int rb = wv * 32 + c * 16 + (lane >> 2);
    gB[c] = W2b + (size_t)e * H_DIM * FFN_D + (size_t)(n0 + rb) * FFN_D + gcol;
  }
  const int dA0 = (wv * 32 + 0)  * 32;
  const int dA1 = (wv * 32 + 16) * 32;

  const int wm = (wv & 1) * 64;
  const int wn = (wv >> 1) * 64;
  const int lr = lane & 15;

  f32x4 acc[4][4];
#pragma unroll
  for (int mi = 0; mi < 4; mi++)
#pragma unroll
    for (int ni = 0; ni < 4; ni++) acc[mi][ni] = (f32x4)0.f;

#define STAGE_DN(KT, BUF)                          \
  do {                                             \
    async16(gA[0] + (KT), &As[BUF][dA0]);          \
    async16(gA[1] + (KT), &As[BUF][dA1]);          \
    async16(gB[0] + (KT), &Bs[BUF][dA0]);          \
    async16(gB[1] + (KT), &Bs[BUF][dA1]);          \
  } while (0)

  STAGE_DN(0, 0);
  STAGE_DN(32, 1);
  asm volatile("s_waitcnt vmcnt(4)" ::: "memory");
  __builtin_amdgcn_s_barrier();

  for (int k = 0; k < FFN_D / 32; ++k) {
    const int kt2 = (k + 2) * 32;
    const int cb  = k % 3;
    if (kt2 < FFN_D) STAGE_DN(kt2, (k + 2) % 3);
    __builtin_amdgcn_sched_barrier(0);

    bf16x8 a[4], b[4];
#pragma unroll
    for (int mi = 0; mi < 4; mi++)
      a[mi] = *(const bf16x8*)&As[cb][(wm + mi * 16 + lr) * 32 + qx];
#pragma unroll
    for (int ni = 0; ni < 4; ni++)
      b[ni] = *(const bf16x8*)&Bs[cb][(wn + ni * 16 + lr) * 32 + qx];
#pragma unroll
    for (int mi = 0; mi < 4; mi++)
#pragma unroll
      for (int ni = 0; ni < 4; ni++)
        acc[mi][ni] = __builtin_amdgcn_mfma_f32_16x16x32_bf16(a[mi], b[ni], acc[mi][ni], 0, 0, 0);

    if (kt2 < FFN_D) asm volatile("s_waitcnt vmcnt(4)" ::: "memory");
    else             asm volatile("s_waitcnt vmcnt(0)" ::: "memory");
    __builtin_amdgcn_sched_barrier(0);
    __builtin_amdgcn_s_barrier();
    __builtin_amdgcn_sched_barrier(0);
  }
#undef STAGE_DN

#pragma unroll
  for (int mi = 0; mi < 4; mi++)
#pragma unroll
    for (int ni = 0; ni < 4; ni++)
#pragma unroll
      for (int r = 0; r < 4; r++) {
        int row = wm + mi * 16 + (lane >> 4) * 4 + r;
        int col = wn + ni * 16 + lr;
        int i = m0 + row;
        if (i < ce)
          Gd[(size_t)(be + i) * H_DIM + n0 + col] = f2bf(acc[mi][ni][r]);
      }
}

// ---------------- K5: combine out[t] = Gd[slot1] + Gd[slot2] ----
__global__ void combine_kernel(const unsigned short* __restrict__ Gd,
                               const int* __restrict__ base,
                               const int* __restrict__ tok2slot,
                               float* __restrict__ out) {
  const int t = blockIdx.x;
  const int v1 = tok2slot[2 * t], v2 = tok2slot[2 * t + 1];
  const int s1 = base[v1 >> 12] + (v1 & 4095);
  const int s2 = base[v2 >> 12] + (v2 & 4095);
  const us4* r1 = (const us4*)(Gd + (size_t)s1 * H_DIM);
  const us4* r2 = (const us4*)(Gd + (size_t)s2 * H_DIM);
  float4* o = (float4*)(out + (size_t)t * H_DIM);
#pragma unroll
  for (int j = 0; j < 2; j++) {
    int i = j * 256 + threadIdx.x;
    us4 a = r1[i], b = r2[i];
    float4 r;
    r.x = bf2f(a.x) + bf2f(b.x);
    r.y = bf2f(a.y) + bf2f(b.y);
    r.z = bf2f(a.z) + bf2f(b.z);
    r.w = bf2f(a.w) + bf2f(b.w);
    o[i] = r;
  }
}

// ---------------- Launch ----------------
extern "C" void kernel_launch(void* const* d_in, const int* in_sizes, int n_in,
                              void* d_out, int out_size, void* d_ws, size_t ws_size,
                              hipStream_t stream) {
  (void)in_sizes; (void)n_in; (void)out_size; (void)ws_size;
  const float* x    = (const float*)d_in[0];
  const float* Wg   = (const float*)d_in[1];
  const float* W1   = (const float*)d_in[2];
  const float* W2   = (const float*)d_in[3];
  const float* W3   = (const float*)d_in[4];
  const float* bias = (const float*)d_in[5];
  float* out = (float*)d_out;

  char* ws = (char*)d_ws;
  const size_t OFF_CNT   = 0;
  const size_t OFF_BASE  = 64;
  const size_t OFF_T2S   = 1024;                       // 32 KB
  const size_t OFF_ROWS  = 65536;                      // 128 KB
  const size_t OFF_WTS   = OFF_ROWS + 131072;          // 128 KB
  const size_t OFF_EPAIR = OFF_WTS + 131072;           // 16 KB
  const size_t OFF_WPAIR = OFF_EPAIR + 16384;          // 32 KB
  const size_t OFF_XB    = 1048576;                    // 16 MB
  const size_t OFF_W1B   = OFF_XB + 16777216;          // 32 MB (Gd aliases after upproj)
  const size_t OFF_W3B   = OFF_W1B + 33554432;         // 32 MB
  const size_t OFF_G     = OFF_W3B + 33554432;         // 16 MB
  const size_t OFF_W2B   = OFF_G + 16777216;           // 32 MB
  // total ~129 MB (proven)

  int*   cnt   = (int*)(ws + OFF_CNT);
  int*   base  = (int*)(ws + OFF_BASE);
  int*   t2s   = (int*)(ws + OFF_T2S);
  int*   rows  = (int*)(ws + OFF_ROWS);
  float* wts   = (float*)(ws + OFF_WTS);
  unsigned* epair = (unsigned*)(ws + OFF_EPAIR);
  float* wpair = (float*)(ws + OFF_WPAIR);
  unsigned short* Xb  = (unsigned short*)(ws + OFF_XB);
  unsigned short* W1b = (unsigned short*)(ws + OFF_W1B);
  unsigned short* W3b = (unsigned short*)(ws + OFF_W3B);
  unsigned short* W2b = (unsigned short*)(ws + OFF_W2B);
  unsigned short* Gd  = (unsigned short*)(ws + OFF_W1B);  // alias: W1b dead after upproj
  unsigned short* G   = (unsigned short*)(ws + OFF_G);

  router_conv_kernel<<<RB_ROUTER + CB_CONV, 256, 0, stream>>>(
      x, Wg, bias, epair, wpair, Xb, W1, W1b, W3, W3b);

  compact_kernel<<<1, 512, 0, stream>>>(epair, wpair, cnt, base, rows, wts, t2s);

  dim3 g2(FFN_D / 64, T_TOK / 128, NE + 1);   // z==NE converts W2 concurrently
  upproj_fast<<<g2, 256, 0, stream>>>(Xb, W1b, W3b, cnt, base, rows, wts, G, W2, W2b);

  dim3 g3(H_DIM / 128, T_TOK / 128, NE);
  downproj_fast<<<g3, 256, 0, stream>>>(G, W2b, cnt, base, Gd);

  combine_kernel<<<T_TOK, 256, 0, stream>>>(Gd, base, t2s, out);
}